// Round 1
// baseline (381.610 us; speedup 1.0000x reference)
//
#include <hip/hip_runtime.h>
#include <cstdint>
#include <cstddef>

#define N 4096
#define M 4096
#define DT 0.01f

#define BM 128
#define BN 128
#define BK 32

typedef short bf16x8 __attribute__((ext_vector_type(8)));
typedef float f32x4 __attribute__((ext_vector_type(4)));

__device__ __forceinline__ unsigned short f2bf(float f) {
  unsigned u = __builtin_bit_cast(unsigned, f);
  return (unsigned short)((u + 0x7fffu + ((u >> 16) & 1u)) >> 16);  // RNE
}

// kbT[i*N + l] = bf16(exp(-x[l*M + i]))  -- transposed so GEMM B-operand is K-contiguous
__global__ void exp_transpose_kernel(const float* __restrict__ x,
                                     unsigned short* __restrict__ kbT) {
  __shared__ float tile[32][33];
  const int i0 = blockIdx.x * 32;
  const int l0 = blockIdx.y * 32;
  const int tx = threadIdx.x, ty = threadIdx.y;  // 32 x 8
#pragma unroll
  for (int r = 0; r < 4; ++r) {
    int row = ty + r * 8;  // l offset
    tile[row][tx] = x[(size_t)(l0 + row) * M + i0 + tx];
  }
  __syncthreads();
#pragma unroll
  for (int r = 0; r < 4; ++r) {
    int row = ty + r * 8;  // i offset
    kbT[(size_t)(i0 + row) * N + l0 + tx] = f2bf(expf(-tile[tx][row]));
  }
}

// T[j*N + l] = bf16(h[j-l]) for l<=j else 0   (lower-triangular Toeplitz)
__global__ void build_T_kernel(const float* __restrict__ h,
                               unsigned short* __restrict__ T) {
  const int j = blockIdx.y;
  const int l0 = (blockIdx.x * blockDim.x + threadIdx.x) * 8;
  unsigned short v[8];
#pragma unroll
  for (int s = 0; s < 8; ++s) {
    int l = l0 + s;
    float hv = (l <= j) ? h[j - l] : 0.0f;
    v[s] = f2bf(hv);
  }
  uint4 pack;
  pack.x = (unsigned)v[0] | ((unsigned)v[1] << 16);
  pack.y = (unsigned)v[2] | ((unsigned)v[3] << 16);
  pack.z = (unsigned)v[4] | ((unsigned)v[5] << 16);
  pack.w = (unsigned)v[6] | ((unsigned)v[7] << 16);
  *reinterpret_cast<uint4*>(&T[(size_t)j * N + l0]) = pack;
}

__device__ __forceinline__ void gld16(void* lds, const void* g) {
  __builtin_amdgcn_global_load_lds(
      (const __attribute__((address_space(1))) void*)g,
      (__attribute__((address_space(3))) void*)lds, 16, 0, 0);
}

// C[j,i] = sum_l T[j,l] * kbT[i,l]; fused epilogue writes final out.
// Triangular: K-loop bounded at j0+BM. Row tiles reversed so heavy blocks go first.
__global__ __launch_bounds__(256)
void gemm_tri_kernel(const unsigned short* __restrict__ Tm,
                     const unsigned short* __restrict__ Bt,
                     const float* __restrict__ x,
                     const float* __restrict__ fe,
                     const float* __restrict__ h,
                     float* __restrict__ out) {
  __shared__ __align__(16) unsigned short As[BM * BK];  // [row j][k], 64B rows
  __shared__ __align__(16) unsigned short Bs[BN * BK];  // [row i][k], 64B rows

  const int tid = threadIdx.x;
  const int wave = tid >> 6, lane = tid & 63;
  const int wr = wave >> 1, wc = wave & 1;       // wave -> 64x64 quadrant
  const int lo16 = lane & 15, hi4 = lane >> 4;
  const int bx = blockIdx.x;
  const int by = (int)gridDim.y - 1 - (int)blockIdx.y;
  const int i0 = bx * BN, j0 = by * BM;

  f32x4 acc[4][4] = {};

  const int nIter = (j0 + BM) / BK;              // causal bound

  // staging geometry: chunk c = pass*256 + tid; row=c>>2 (4x16B chunks/row)
  const int row0 = tid >> 2;
  const int cb = (tid & 3) * 16;
  const size_t strideB = (size_t)N * 2;          // 8192 B per matrix row

  for (int t = 0; t < nIter; ++t) {
    const int l0 = t * BK;
    const char* Abase = (const char*)Tm + (size_t)j0 * strideB + (size_t)l0 * 2;
    const char* Bbase = (const char*)Bt + (size_t)i0 * strideB + (size_t)l0 * 2;
    char* AsB = (char*)As;
    char* BsB = (char*)Bs;
    // 8KB per tile = 2 passes of (256 threads x 16B); LDS dst is wave-uniform base,
    // HW adds lane*16.
    gld16(AsB + wave * 1024,        Abase + (size_t)row0 * strideB + cb);
    gld16(AsB + 4096 + wave * 1024, Abase + (size_t)(row0 + 64) * strideB + cb);
    gld16(BsB + wave * 1024,        Bbase + (size_t)row0 * strideB + cb);
    gld16(BsB + 4096 + wave * 1024, Bbase + (size_t)(row0 + 64) * strideB + cb);
    __syncthreads();

    bf16x8 af[4], bfr[4];
#pragma unroll
    for (int mt = 0; mt < 4; ++mt) {
      int row = wr * 64 + mt * 16 + lo16;
      af[mt] = *reinterpret_cast<const bf16x8*>((const char*)As + row * 64 + hi4 * 16);
    }
#pragma unroll
    for (int nt = 0; nt < 4; ++nt) {
      int row = wc * 64 + nt * 16 + lo16;
      bfr[nt] = *reinterpret_cast<const bf16x8*>((const char*)Bs + row * 64 + hi4 * 16);
    }
#pragma unroll
    for (int mt = 0; mt < 4; ++mt) {
#pragma unroll
      for (int nt = 0; nt < 4; ++nt) {
        acc[mt][nt] = __builtin_amdgcn_mfma_f32_16x16x32_bf16(
            af[mt], bfr[nt], acc[mt][nt], 0, 0, 0);
      }
    }
    __syncthreads();
  }

  // Epilogue: out[j,i] = fe[j] + dt*(0.5*k0[i]*h[j] - 0.5*k[j,i]*h[0] - C[j,i])
  const float h0 = h[0];
#pragma unroll
  for (int nt = 0; nt < 4; ++nt) {
    const int i = i0 + wc * 64 + nt * 16 + lo16;
    const float k0i = expf(-x[i]);
#pragma unroll
    for (int mt = 0; mt < 4; ++mt) {
#pragma unroll
      for (int r = 0; r < 4; ++r) {
        const int j = j0 + wr * 64 + mt * 16 + hi4 * 4 + r;
        const float kji = expf(-x[(size_t)j * M + i]);
        out[(size_t)j * M + i] =
            fe[j] + DT * (0.5f * k0i * h[j] - 0.5f * kji * h0 - acc[mt][nt][r]);
      }
    }
  }
}

extern "C" void kernel_launch(void* const* d_in, const int* in_sizes, int n_in,
                              void* d_out, int out_size, void* d_ws, size_t ws_size,
                              hipStream_t stream) {
  const float* x  = (const float*)d_in[0];
  const float* fe = (const float*)d_in[1];
  const float* h  = (const float*)d_in[2];
  float* out = (float*)d_out;

  const size_t matBytes = (size_t)N * N * sizeof(unsigned short);  // 32 MiB
  if (ws_size < 2 * matBytes) return;  // loud failure if scratch too small

  unsigned short* kbT = (unsigned short*)d_ws;
  unsigned short* Tm  = (unsigned short*)((char*)d_ws + matBytes);

  exp_transpose_kernel<<<dim3(M / 32, N / 32), dim3(32, 8), 0, stream>>>(x, kbT);
  build_T_kernel<<<dim3(2, N), 256, 0, stream>>>(h, Tm);
  gemm_tri_kernel<<<dim3(M / BN, N / BM), 256, 0, stream>>>(Tm, kbT, x, fe, h, out);
}

// Round 2
// 263.717 us; speedup vs baseline: 1.4470x; 1.4470x over previous
//
#include <hip/hip_runtime.h>
#include <cstdint>
#include <cstddef>

#define N 4096
#define M 4096
#define DT 0.01f

#define BM 128
#define BN 128
#define BK 32

typedef short bf16x8 __attribute__((ext_vector_type(8)));
typedef float f32x4 __attribute__((ext_vector_type(4)));

__device__ __forceinline__ unsigned short f2bf(float f) {
  unsigned u = __builtin_bit_cast(unsigned, f);
  return (unsigned short)((u + 0x7fffu + ((u >> 16) & 1u)) >> 16);  // RNE
}

__device__ __forceinline__ void atomAddF(float* p, float v) {
  unsafeAtomicAdd(p, v);  // global_atomic_add_f32, device scope, no-return
}

// Fused: kbT[i*N + l] = bf16(exp(-x[l*M+i]))  (transposed, K-contiguous B-operand)
//        out[l*M + i] = fe[l] + DT*(0.5*k0[i]*h[l] - 0.5*k[l,i]*h[0])   (affine init)
// GEMM blocks later atomic-add the -DT*C convolution term on top.
__global__ __launch_bounds__(256)
void exp_tr_init_kernel(const float* __restrict__ x, const float* __restrict__ fe,
                        const float* __restrict__ h, unsigned short* __restrict__ kbT,
                        float* __restrict__ out) {
  __shared__ __align__(16) unsigned short tileT[64][72];  // [i][l], row 144B (16B-aligned)
  const int i0 = blockIdx.x * 64, l0 = blockIdx.y * 64;
  const int tid = threadIdx.x;
  const int ci = (tid & 15) * 4;  // i offset within tile
  const int r0 = tid >> 4;        // l offset base
  const float h0 = h[0];
  const float4 x0v = *reinterpret_cast<const float4*>(&x[i0 + ci]);  // x row 0 (L2-hot)
  const float k00 = expf(-x0v.x), k01 = expf(-x0v.y),
              k02 = expf(-x0v.z), k03 = expf(-x0v.w);
#pragma unroll
  for (int rr = 0; rr < 4; ++rr) {
    const int l = l0 + r0 + rr * 16;
    const float4 xv = *reinterpret_cast<const float4*>(&x[(size_t)l * M + i0 + ci]);
    const float kb0 = expf(-xv.x), kb1 = expf(-xv.y),
                kb2 = expf(-xv.z), kb3 = expf(-xv.w);
    const float hj = h[l], fj = fe[l];
    float4 o;
    o.x = fj + DT * (0.5f * k00 * hj - 0.5f * kb0 * h0);
    o.y = fj + DT * (0.5f * k01 * hj - 0.5f * kb1 * h0);
    o.z = fj + DT * (0.5f * k02 * hj - 0.5f * kb2 * h0);
    o.w = fj + DT * (0.5f * k03 * hj - 0.5f * kb3 * h0);
    *reinterpret_cast<float4*>(&out[(size_t)l * M + i0 + ci]) = o;
    const int lr = r0 + rr * 16;
    tileT[ci + 0][lr] = f2bf(kb0);
    tileT[ci + 1][lr] = f2bf(kb1);
    tileT[ci + 2][lr] = f2bf(kb2);
    tileT[ci + 3][lr] = f2bf(kb3);
  }
  __syncthreads();
  const int ir = tid >> 2, cc = tid & 3;
#pragma unroll
  for (int s = 0; s < 2; ++s) {
    const int ch = cc + s * 4;  // 8 x 16B chunks per 128B row
    bf16x8 v = *reinterpret_cast<const bf16x8*>(&tileT[ir][ch * 8]);
    *reinterpret_cast<bf16x8*>(&kbT[(size_t)(i0 + ir) * N + l0 + ch * 8]) = v;
  }
}

// T[j*N + l] = bf16(h[j-l]) for l<=j else 0   (lower-triangular Toeplitz)
__global__ void build_T_kernel(const float* __restrict__ h,
                               unsigned short* __restrict__ T) {
  const int j = blockIdx.y;
  const int l0 = (blockIdx.x * blockDim.x + threadIdx.x) * 8;
  unsigned short v[8];
#pragma unroll
  for (int s = 0; s < 8; ++s) {
    int l = l0 + s;
    float hv = (l <= j) ? h[j - l] : 0.0f;
    v[s] = f2bf(hv);
  }
  uint4 pack;
  pack.x = (unsigned)v[0] | ((unsigned)v[1] << 16);
  pack.y = (unsigned)v[2] | ((unsigned)v[3] << 16);
  pack.z = (unsigned)v[4] | ((unsigned)v[5] << 16);
  pack.w = (unsigned)v[6] | ((unsigned)v[7] << 16);
  *reinterpret_cast<uint4*>(&T[(size_t)j * N + l0]) = pack;
}

__device__ __forceinline__ void gld16(void* lds, const void* g) {
  __builtin_amdgcn_global_load_lds(
      (const __attribute__((address_space(1))) void*)g,
      (__attribute__((address_space(3))) void*)lds, 16, 0, 0);
}

// Split-K triangular GEMM: out[j,i] -= DT * sum_l T[j,l]*kbT[i,l] over this unit's
// K-chunk. Units: 32 cols x 48 y-units; y-unit -> (row-block by, K-chunk) with
// chunks capped at 64 BK-iters for near-uniform load. Heavy chunks dispatch first.
__global__ __launch_bounds__(256)
void gemm_tri_kernel(const unsigned short* __restrict__ Tm,
                     const unsigned short* __restrict__ Bt,
                     float* __restrict__ out) {
  __shared__ __align__(16) unsigned short As[BM * BK];  // [row j][k], 64B rows
  __shared__ __align__(16) unsigned short Bs[BN * BK];  // [row i][k], 64B rows

  const int tid = threadIdx.x;
  const int wave = tid >> 6, lane = tid & 63;
  const int wr = wave >> 1, wc = wave & 1;       // wave -> 64x64 quadrant
  const int lo16 = lane & 15, hi4 = lane >> 4;
  const int i0 = blockIdx.x * BN;

  // unit decode (reversed so 64-iter chunks dispatch first)
  const int ur = 47 - (int)blockIdx.y;
  int by, t0, t1;
  if (ur < 32) {
    by = ur;
    t0 = 0;
    const int full = 4 * ur + 4;
    t1 = full < 64 ? full : 64;
  } else {
    by = ur - 16;          // rows 16..31, second chunk
    t0 = 64;
    t1 = 4 * by + 4;
  }
  const int j0 = by * BM;

  f32x4 acc[4][4] = {};

  // staging geometry: chunk c = pass*256 + tid; row = c>>2 (4 x 16B chunks/row)
  const int row0 = tid >> 2;
  const int cb = (tid & 3) * 16;
  const size_t strideB = (size_t)N * 2;  // 8192 B per matrix row

  for (int t = t0; t < t1; ++t) {
    const int l0 = t * BK;
    const char* Abase = (const char*)Tm + (size_t)j0 * strideB + (size_t)l0 * 2;
    const char* Bbase = (const char*)Bt + (size_t)i0 * strideB + (size_t)l0 * 2;
    char* AsB = (char*)As;
    char* BsB = (char*)Bs;
    gld16(AsB + wave * 1024,        Abase + (size_t)row0 * strideB + cb);
    gld16(AsB + 4096 + wave * 1024, Abase + (size_t)(row0 + 64) * strideB + cb);
    gld16(BsB + wave * 1024,        Bbase + (size_t)row0 * strideB + cb);
    gld16(BsB + 4096 + wave * 1024, Bbase + (size_t)(row0 + 64) * strideB + cb);
    __syncthreads();

    bf16x8 af[4], bfr[4];
#pragma unroll
    for (int mt = 0; mt < 4; ++mt) {
      int row = wr * 64 + mt * 16 + lo16;
      af[mt] = *reinterpret_cast<const bf16x8*>((const char*)As + row * 64 + hi4 * 16);
    }
#pragma unroll
    for (int nt = 0; nt < 4; ++nt) {
      int row = wc * 64 + nt * 16 + lo16;
      bfr[nt] = *reinterpret_cast<const bf16x8*>((const char*)Bs + row * 64 + hi4 * 16);
    }
#pragma unroll
    for (int mt = 0; mt < 4; ++mt) {
#pragma unroll
      for (int nt = 0; nt < 4; ++nt) {
        acc[mt][nt] = __builtin_amdgcn_mfma_f32_16x16x32_bf16(
            af[mt], bfr[nt], acc[mt][nt], 0, 0, 0);
      }
    }
    __syncthreads();
  }

  // Epilogue: atomically accumulate -DT * partial into pre-initialized out.
#pragma unroll
  for (int nt = 0; nt < 4; ++nt) {
    const int i = i0 + wc * 64 + nt * 16 + lo16;
#pragma unroll
    for (int mt = 0; mt < 4; ++mt) {
#pragma unroll
      for (int r = 0; r < 4; ++r) {
        const int j = j0 + wr * 64 + mt * 16 + hi4 * 4 + r;
        atomAddF(&out[(size_t)j * M + i], -DT * acc[mt][nt][r]);
      }
    }
  }
}

extern "C" void kernel_launch(void* const* d_in, const int* in_sizes, int n_in,
                              void* d_out, int out_size, void* d_ws, size_t ws_size,
                              hipStream_t stream) {
  const float* x  = (const float*)d_in[0];
  const float* fe = (const float*)d_in[1];
  const float* h  = (const float*)d_in[2];
  float* out = (float*)d_out;

  const size_t matBytes = (size_t)N * N * sizeof(unsigned short);  // 32 MiB
  if (ws_size < 2 * matBytes) return;

  unsigned short* kbT = (unsigned short*)d_ws;
  unsigned short* Tm  = (unsigned short*)((char*)d_ws + matBytes);

  exp_tr_init_kernel<<<dim3(M / 64, N / 64), 256, 0, stream>>>(x, fe, h, kbT, out);
  build_T_kernel<<<dim3(2, N), 256, 0, stream>>>(h, Tm);
  gemm_tri_kernel<<<dim3(M / BN, 48), 256, 0, stream>>>(Tm, kbT, out);
}